// Round 4
// baseline (125.242 us; speedup 1.0000x reference)
//
#include <hip/hip_runtime.h>

#define RADIUS 5
#define WIN 9
#define BB 4
#define KK 4
#define HH 224
#define WW 224
#define HW (HH * WW)
#define PD 234                 // HH + 2*RADIUS
#define PAREA (PD * PD)        // 54756
#define NBUCKET 64
#define PARTIAL_FLOATS (NBUCKET * BB * 8)   // 2048 floats

#define CHUNK_ELEMS 2304                    // elements (weights) per wave
#define ITERS 9                             // 2304 / 256 (64 lanes x float4)
#define WAVES_PER_B 1764                    // HW*81 / 2304  (exact)
#define WAVES_TOTAL (BB * WAVES_PER_B)      // 7056

// d_ws layout (floats):
//   [0, 2048)   : partial buckets [bucket][b][8] (0..3 A_k, 4..7 V_k)
//   [2048, ...) : padded seg P[b][r][c][k] as float4 per (r,c)

// ---------- pre-pass: seg [B,K,H,W] -> zero-padded [B,PD,PD,K] (float4) ----------
__global__ __launch_bounds__(256) void ncuts_pad(
    const float* __restrict__ seg, float4* __restrict__ pseg)
{
    const int tid = blockIdx.x * 256 + threadIdx.x;
    if (tid >= BB * PAREA) return;
    const int b  = tid / PAREA;
    const int rc = tid - b * PAREA;
    const int r  = rc / PD;
    const int c  = rc - r * PD;
    const int hh = r - RADIUS;
    const int ww = c - RADIUS;
    float4 v = {0.f, 0.f, 0.f, 0.f};
    if (hh >= 0 && hh < HH && ww >= 0 && ww < WW) {
        const float* sb = seg + (size_t)b * KK * HW + hh * WW + ww;
        v.x = sb[0 * HW];
        v.y = sb[1 * HW];
        v.z = sb[2 * HW];
        v.w = sb[3 * HW];
    }
    pseg[tid] = v;
}

// ---------- main: flat-order weight stream, float4 loads, 4 taps/lane/iter ----------
// wave `wid` owns weight elements [wid*2304, (wid+1)*2304), entirely within one b.
// iteration t: lane L loads float4 at element (t*64 + L)*4 within the chunk.
__global__ __launch_bounds__(256) void ncuts_main(
    const float4* __restrict__ weight4,
    const float4* __restrict__ pseg,
    float* __restrict__ partial)
{
    const int lane = threadIdx.x & 63;
    const int wid  = blockIdx.x * 4 + (threadIdx.x >> 6);   // 0..7055
    const int b    = wid / WAVES_PER_B;                     // wave-uniform

    const float4* wb = weight4 + (size_t)wid * (CHUNK_ELEMS / 4);  // 576 float4s
    const float4* pb = pseg + (size_t)b * PAREA;

    float a0 = 0.f, a1 = 0.f, a2 = 0.f, a3 = 0.f;
    float v0 = 0.f, v1 = 0.f, v2 = 0.f, v3 = 0.f;

    #pragma unroll 3
    for (int t = 0; t < ITERS; ++t) {
        const float4 wv4 = wb[t * 64 + lane];   // address affine in t -> issues early

        // decode first element of this lane's 4-tap group
        const uint32_t e0  = (uint32_t)wid * CHUNK_ELEMS + (uint32_t)(t * 256 + lane * 4);
        const uint32_t p   = e0 / 81u;                 // pixel id (global)
        int tap            = (int)(e0 - 81u * p);
        const uint32_t rem = p - (uint32_t)b * HW;     // pixel within b
        uint32_t h         = rem / (uint32_t)WW;
        uint32_t w         = rem - h * (uint32_t)WW;
        int roff           = (int)(h * PD + w);

        float4 o = pb[roff + RADIUS * PD + RADIUS];    // own pixel (cache hit)
        const float wv_[4] = { wv4.x, wv4.y, wv4.z, wv4.w };

        #pragma unroll
        for (int j = 0; j < 4; ++j) {
            const int m = (tap * 57) >> 9;             // tap/9, exact for tap<81
            const int n = tap - 9 * m;
            const float4 s = pb[roff + m * PD + n];    // window tap (cache hit)
            const float wv = wv_[j];
            a0 = fmaf(wv * s.x, o.x, a0);
            a1 = fmaf(wv * s.y, o.y, a1);
            a2 = fmaf(wv * s.z, o.z, a2);
            a3 = fmaf(wv * s.w, o.w, a3);
            v0 = fmaf(wv, o.x, v0);
            v1 = fmaf(wv, o.y, v1);
            v2 = fmaf(wv, o.z, v2);
            v3 = fmaf(wv, o.w, v3);
            if (j < 3) {                               // static guard: no dead tail work
                if (++tap >= 81) {                     // pixel advance (stays within b)
                    tap = 0;
                    if (++w == WW) { w = 0; ++h; }
                    roff = (int)(h * PD + w);
                    o = pb[roff + RADIUS * PD + RADIUS];
                }
            }
        }
    }

    float vals[8] = { a0, a1, a2, a3, v0, v1, v2, v3 };

    #pragma unroll
    for (int i = 0; i < 8; ++i) {
        float v = vals[i];
        v += __shfl_down(v, 32);
        v += __shfl_down(v, 16);
        v += __shfl_down(v, 8);
        v += __shfl_down(v, 4);
        v += __shfl_down(v, 2);
        v += __shfl_down(v, 1);
        vals[i] = v;
    }

    if (lane == 0) {
        const int bucket = wid & (NBUCKET - 1);
        float* dst = partial + (bucket * BB + b) * 8;
        #pragma unroll
        for (int i = 0; i < 8; ++i)
            atomicAdd(dst + i, vals[i]);
    }
}

// ---------- final: fold buckets, compute loss ----------
__global__ __launch_bounds__(64) void ncuts_final(
    const float* __restrict__ partial, float* __restrict__ out)
{
    __shared__ float sums[32];
    const int t = threadIdx.x;
    if (t < 32) {
        const int b = t >> 3;
        const int i = t & 7;
        float s = 0.f;
        for (int bucket = 0; bucket < NBUCKET; ++bucket)
            s += partial[(bucket * BB + b) * 8 + i];
        sums[b * 8 + i] = s;
    }
    __syncthreads();
    if (t == 0) {
        float total = 0.f;
        for (int b = 0; b < BB; ++b) {
            float assoc = 0.f;
            for (int k = 0; k < KK; ++k) {
                const float A = sums[b * 8 + k];
                const float V = sums[b * 8 + 4 + k];
                assoc += A / V;
            }
            total += (float)KK - assoc;
        }
        out[0] = total;
    }
}

extern "C" void kernel_launch(void* const* d_in, const int* in_sizes, int n_in,
                              void* d_out, int out_size, void* d_ws, size_t ws_size,
                              hipStream_t stream) {
    const float* seg     = (const float*)d_in[0];
    const float4* weight = (const float4*)d_in[1];
    float* out     = (float*)d_out;
    float* wsf     = (float*)d_ws;
    float* partial = wsf;
    float4* pseg   = (float4*)(wsf + PARTIAL_FLOATS);   // byte offset 8192, 16B aligned

    hipMemsetAsync(d_ws, 0, PARTIAL_FLOATS * sizeof(float), stream);

    {
        const int total = BB * PAREA;           // 219024
        const int grid  = (total + 255) / 256;  // 856
        hipLaunchKernelGGL(ncuts_pad, dim3(grid), dim3(256), 0, stream, seg, pseg);
    }
    {
        const int grid = WAVES_TOTAL / 4;       // 1764 blocks x 4 waves
        hipLaunchKernelGGL(ncuts_main, dim3(grid), dim3(256), 0, stream,
                           weight, pseg, partial);
    }
    hipLaunchKernelGGL(ncuts_final, dim3(1), dim3(64), 0, stream, partial, out);
}

// Round 5
// 123.005 us; speedup vs baseline: 1.0182x; 1.0182x over previous
//
#include <hip/hip_runtime.h>

#define RADIUS 5
#define WIN 9
#define BB 4
#define KK 4
#define HH 224
#define WW 224
#define HW (HH * WW)
#define PD 234                 // HH + 2*RADIUS
#define PAREA (PD * PD)        // 54756
#define NBUCKET 64
#define PARTIAL_FLOATS (NBUCKET * BB * 8)   // 2048 floats

#define PX_PER_BLOCK 64
#define BLOCKS_TOTAL (BB * HW / PX_PER_BLOCK)   // 3136
#define WF4_PER_BLOCK (PX_PER_BLOCK * 81 / 4)   // 1296 float4 of weights per block

// d_ws layout (floats):
//   [0, 2048)   : partial buckets [bucket][b][8] (0..3 A_k, 4..7 V_k)
//   [2048, ...) : padded seg P[b][r][c][k] as float4 per (r,c)

// ---------- pre-pass: seg [B,K,H,W] -> zero-padded [B,PD,PD,K] (float4) ----------
__global__ __launch_bounds__(256) void ncuts_pad(
    const float* __restrict__ seg, float4* __restrict__ pseg)
{
    const int tid = blockIdx.x * 256 + threadIdx.x;
    if (tid >= BB * PAREA) return;
    const int b  = tid / PAREA;
    const int rc = tid - b * PAREA;
    const int r  = rc / PD;
    const int c  = rc - r * PD;
    const int hh = r - RADIUS;
    const int ww = c - RADIUS;
    float4 v = {0.f, 0.f, 0.f, 0.f};
    if (hh >= 0 && hh < HH && ww >= 0 && ww < WW) {
        const float* sb = seg + (size_t)b * KK * HW + hh * WW + ww;
        v.x = sb[0 * HW];
        v.y = sb[1 * HW];
        v.z = sb[2 * HW];
        v.w = sb[3 * HW];
    }
    pseg[tid] = v;
}

// tap range [T0,T1) with compile-time (m,n): ds_read imm offsets + imm global offsets
template<int T0, int T1>
__device__ __forceinline__ void do_taps(const float* __restrict__ wl,
                                        const float4* __restrict__ pb, int roff,
                                        float& a0, float& a1, float& a2, float& a3,
                                        float& wsum)
{
    #pragma unroll
    for (int tap = T0; tap < T1; ++tap) {
        const int m = tap / 9;           // compile-time
        const int n = tap - 9 * m;       // compile-time
        const float wv = wl[tap];        // ds_read_b32, imm offset, 2-way bank (free)
        const float4 s = pb[roff + m * PD + n];   // lane-consecutive float4 (cache hit)
        a0 = fmaf(wv, s.x, a0);
        a1 = fmaf(wv, s.y, a1);
        a2 = fmaf(wv, s.z, a2);
        a3 = fmaf(wv, s.w, a3);
        wsum += wv;
    }
}

// ---------- main: 64 px per block, LDS-staged weights, taps split across 4 waves ----------
__global__ __launch_bounds__(256, 7) void ncuts_main(
    const float4* __restrict__ weight4,
    const float4* __restrict__ pseg,
    float* __restrict__ partial)
{
    __shared__ float wlds[PX_PER_BLOCK * 81];   // 20736 B

    const int tid  = threadIdx.x;
    const int lane = tid & 63;
    const int ws   = tid >> 6;

    // --- stage the block's weight slab, fully coalesced float4 ---
    const float4* wsrc = weight4 + (size_t)blockIdx.x * WF4_PER_BLOCK;
    float4* wdst = (float4*)wlds;
    #pragma unroll
    for (int it = 0; it < 6; ++it) {
        const int idx = it * 256 + tid;
        if (idx < WF4_PER_BLOCK) wdst[idx] = wsrc[idx];
    }
    __syncthreads();

    // --- per-lane pixel ---
    const int px  = blockIdx.x * PX_PER_BLOCK + lane;
    const int b   = px / HW;                    // block-uniform (784 blocks per b)
    const int rem = px - b * HW;
    const int h   = rem / WW;
    const int w   = rem - h * WW;
    const int roff = h * PD + w;

    const float4* pb = pseg + (size_t)b * PAREA;
    const float* wl  = &wlds[lane * 81];

    float a0 = 0.f, a1 = 0.f, a2 = 0.f, a3 = 0.f, wsum = 0.f;

    switch (ws) {                                // wave-uniform branch
        case 0: do_taps< 0, 21>(wl, pb, roff, a0, a1, a2, a3, wsum); break;
        case 1: do_taps<21, 41>(wl, pb, roff, a0, a1, a2, a3, wsum); break;
        case 2: do_taps<41, 61>(wl, pb, roff, a0, a1, a2, a3, wsum); break;
        default: do_taps<61, 81>(wl, pb, roff, a0, a1, a2, a3, wsum); break;
    }

    const float4 o = pb[roff + RADIUS * PD + RADIUS];   // own pixel

    float vals[8] = { a0 * o.x, a1 * o.y, a2 * o.z, a3 * o.w,
                      wsum * o.x, wsum * o.y, wsum * o.z, wsum * o.w };

    #pragma unroll
    for (int i = 0; i < 8; ++i) {
        float v = vals[i];
        v += __shfl_down(v, 32);
        v += __shfl_down(v, 16);
        v += __shfl_down(v, 8);
        v += __shfl_down(v, 4);
        v += __shfl_down(v, 2);
        v += __shfl_down(v, 1);
        vals[i] = v;
    }

    if (lane == 0) {
        const int bucket = (blockIdx.x * 4 + ws) & (NBUCKET - 1);
        float* dst = partial + (bucket * BB + b) * 8;
        #pragma unroll
        for (int i = 0; i < 8; ++i)
            atomicAdd(dst + i, vals[i]);
    }
}

// ---------- final: fold buckets, compute loss ----------
__global__ __launch_bounds__(64) void ncuts_final(
    const float* __restrict__ partial, float* __restrict__ out)
{
    __shared__ float sums[32];
    const int t = threadIdx.x;
    if (t < 32) {
        const int b = t >> 3;
        const int i = t & 7;
        float s = 0.f;
        for (int bucket = 0; bucket < NBUCKET; ++bucket)
            s += partial[(bucket * BB + b) * 8 + i];
        sums[b * 8 + i] = s;
    }
    __syncthreads();
    if (t == 0) {
        float total = 0.f;
        for (int b = 0; b < BB; ++b) {
            float assoc = 0.f;
            for (int k = 0; k < KK; ++k) {
                const float A = sums[b * 8 + k];
                const float V = sums[b * 8 + 4 + k];
                assoc += A / V;
            }
            total += (float)KK - assoc;
        }
        out[0] = total;
    }
}

extern "C" void kernel_launch(void* const* d_in, const int* in_sizes, int n_in,
                              void* d_out, int out_size, void* d_ws, size_t ws_size,
                              hipStream_t stream) {
    const float* seg     = (const float*)d_in[0];
    const float4* weight = (const float4*)d_in[1];
    float* out     = (float*)d_out;
    float* wsf     = (float*)d_ws;
    float* partial = wsf;
    float4* pseg   = (float4*)(wsf + PARTIAL_FLOATS);   // byte offset 8192, 16B aligned

    hipMemsetAsync(d_ws, 0, PARTIAL_FLOATS * sizeof(float), stream);

    {
        const int total = BB * PAREA;           // 219024
        const int grid  = (total + 255) / 256;  // 856
        hipLaunchKernelGGL(ncuts_pad, dim3(grid), dim3(256), 0, stream, seg, pseg);
    }
    {
        hipLaunchKernelGGL(ncuts_main, dim3(BLOCKS_TOTAL), dim3(256), 0, stream,
                           weight, pseg, partial);
    }
    hipLaunchKernelGGL(ncuts_final, dim3(1), dim3(64), 0, stream, partial, out);
}